// Round 13
// baseline (719.966 us; speedup 1.0000x reference)
//
#include <hip/hip_runtime.h>

#define NUM_E 100000
#define NUM_M 200000
#define DIM   128
#define HID   256
#define NG    64
#define TITER 3
#define NB_SCAN 98   // ceil(NUM_E/1024)
#define GS_ER 128    // edges per block in graph_sum

typedef __attribute__((ext_vector_type(8))) short bf16x8;
typedef __attribute__((ext_vector_type(4))) float f32x4;

__device__ __forceinline__ unsigned short f2bf(float f) {
  unsigned u = __float_as_uint(f);
  u += 0x7FFF + ((u >> 16) & 1);          // RNE
  return (unsigned short)(u >> 16);
}
__device__ __forceinline__ float bf2f(unsigned short h) {
  return __uint_as_float(((unsigned)h) << 16);
}
__device__ __forceinline__ float sigmoidf_(float v) {
  return 1.f / (1.f + __expf(-v));
}
__device__ __forceinline__ float tanhf_(float u) {
  u = fminf(fmaxf(u, -15.f), 15.f);
  float ex = __expf(-2.f * u);
  return (1.f - ex) / (1.f + ex);
}
__device__ __forceinline__ float relu_(float v) { return fmaxf(v, 0.f); }

#define MFMA(a, b, c) __builtin_amdgcn_mfma_f32_16x16x32_bf16((a), (b), (c), 0, 0, 0)

// ---------------- CSR: histogram (also zeroes gs) ----------------
__global__ void hist_kernel(const int* __restrict__ second, int* __restrict__ counts,
                            float4* __restrict__ gs4) {
  int m = blockIdx.x * blockDim.x + threadIdx.x;
  if (m < NG * DIM / 4) gs4[m] = make_float4(0.f, 0.f, 0.f, 0.f);
  if (m < NUM_M) atomicAdd(&counts[second[m]], 1);
}

// ---------------- 3-kernel parallel scan (coalesced; R10-proven) ----------------
__global__ __launch_bounds__(256) void scan1_kernel(const int* __restrict__ counts,
                                                    int* __restrict__ partials) {
  __shared__ int sh[256];
  int b = blockIdx.x, t = threadIdx.x;
  int i0 = b * 1024 + t * 4;
  int c0 = (i0 + 0 < NUM_E) ? counts[i0 + 0] : 0;
  int c1 = (i0 + 1 < NUM_E) ? counts[i0 + 1] : 0;
  int c2 = (i0 + 2 < NUM_E) ? counts[i0 + 2] : 0;
  int c3 = (i0 + 3 < NUM_E) ? counts[i0 + 3] : 0;
  int tsum = c0 + c1 + c2 + c3;
  sh[t] = tsum;
  __syncthreads();
  for (int off = 1; off < 256; off <<= 1) {
    int v = (t >= off) ? sh[t - off] : 0;
    __syncthreads();
    sh[t] += v;
    __syncthreads();
  }
  if (t == 255) partials[b] = sh[255];
}

__global__ void scan2_kernel(const int* __restrict__ partials, int* __restrict__ base,
                             int* __restrict__ rowptr) {
  if (threadIdx.x == 0) {
    int run = 0;
    for (int b = 0; b < NB_SCAN; ++b) { base[b] = run; run += partials[b]; }
    rowptr[NUM_E] = NUM_M;
  }
}

__global__ __launch_bounds__(256) void scan3_kernel(const int* __restrict__ counts,
                                                    const int* __restrict__ base,
                                                    int* __restrict__ rowptr) {
  __shared__ int sh[256];
  int b = blockIdx.x, t = threadIdx.x;
  int i0 = b * 1024 + t * 4;
  int c0 = (i0 + 0 < NUM_E) ? counts[i0 + 0] : 0;
  int c1 = (i0 + 1 < NUM_E) ? counts[i0 + 1] : 0;
  int c2 = (i0 + 2 < NUM_E) ? counts[i0 + 2] : 0;
  int c3 = (i0 + 3 < NUM_E) ? counts[i0 + 3] : 0;
  int tsum = c0 + c1 + c2 + c3;
  sh[t] = tsum;
  __syncthreads();
  for (int off = 1; off < 256; off <<= 1) {
    int v = (t >= off) ? sh[t - off] : 0;
    __syncthreads();
    sh[t] += v;
    __syncthreads();
  }
  int p = base[b] + (sh[t] - tsum);
  if (i0 + 0 < NUM_E) rowptr[i0 + 0] = p;
  if (i0 + 1 < NUM_E) rowptr[i0 + 1] = p + c0;
  if (i0 + 2 < NUM_E) rowptr[i0 + 2] = p + c0 + c1;
  if (i0 + 3 < NUM_E) rowptr[i0 + 3] = p + c0 + c1 + c2;
}

__global__ void scatter_kernel(const int* __restrict__ second,
                               const int* __restrict__ rowptr,
                               int* __restrict__ cursor, int* __restrict__ order) {
  int m = blockIdx.x * blockDim.x + threadIdx.x;
  if (m < NUM_M) {
    int e = second[m];
    int pos = atomicAdd(&cursor[e], 1);
    int idx = rowptr[e] + pos;
    if (idx < rowptr[e + 1]) order[idx] = m;   // guard: rocprof replay re-runs w/o re-zero
  }
}

// ---------------- fused prep: fp32->bf16 cvt + all weight packs ----------------
__device__ __forceinline__ void pack_range(
    const float* __restrict__ srcA, const float* __restrict__ srcB, int KrowsA,
    int N, int src_ld, int col_off, unsigned short* __restrict__ dst, int idx) {
  int l = idx & 63;
  int t = idx >> 6;
  int NF = N / 16;
  int nf = t % NF;
  int ks = t / NF;
  int n = nf * 16 + (l & 15) + col_off;
  int k0 = ks * 32 + (l >> 4) * 8;
  unsigned short o[8];
  #pragma unroll
  for (int j = 0; j < 8; ++j) {
    int k = k0 + j;
    const float* src = (k < KrowsA) ? (srcA + (size_t)k * src_ld)
                                    : (srcB + (size_t)(k - KrowsA) * src_ld);
    o[j] = f2bf(src[n]);
  }
  ushort4* d = (ushort4*)(dst + (size_t)idx * 8);
  d[0] = make_ushort4(o[0], o[1], o[2], o[3]);
  d[1] = make_ushort4(o[4], o[5], o[6], o[7]);
}

// grid covers n4 = NUM_E*DIM/4 threads; ids < 24576 also pack weights
__global__ __launch_bounds__(256) void prep_kernel(
    const float4* __restrict__ ls4, ushort4* __restrict__ lsb4, int n4,
    const float* __restrict__ mW1, const float* __restrict__ mW2,
    const float* __restrict__ gk,  const float* __restrict__ gr,
    unsigned short* __restrict__ W1p,  unsigned short* __restrict__ W2p,
    unsigned short* __restrict__ Wzrp, unsigned short* __restrict__ Wkhp,
    unsigned short* __restrict__ Wrhp) {
  int i = blockIdx.x * 256 + threadIdx.x;
  if (i < n4) {
    float4 v = ls4[i];
    ushort4 o;
    o.x = f2bf(v.x); o.y = f2bf(v.y); o.z = f2bf(v.z); o.w = f2bf(v.w);
    lsb4[i] = o;
  }
  if      (i < 8192)  pack_range(mW1, mW1, 256, 256, 256, 0,   W1p,  i);
  else if (i < 12288) pack_range(mW2, mW2, 256, 128, 128, 0,   W2p,  i - 8192);
  else if (i < 20480) pack_range(gk,  gr,  128, 256, 384, 0,   Wzrp, i - 12288);
  else if (i < 22528) pack_range(gk,  gk,  128, 128, 384, 256, Wkhp, i - 20480);
  else if (i < 24576) pack_range(gr,  gr,  128, 128, 384, 256, Wrhp, i - 22528);
}

// ---------------- message MLP: persistent weights + pipelined gather (R9) ----------------
__global__ __launch_bounds__(256, 1) void msg_kernel(
    const unsigned short* __restrict__ lsb,   // [E,128] bf16
    const int* __restrict__ first, const int* __restrict__ second,
    const int* __restrict__ order,            // [M] permutation
    const unsigned short* __restrict__ W1p,   // packed [8 ks][16 nf][64][8]
    const float* __restrict__ b1,
    const unsigned short* __restrict__ W2p,   // packed [8 ks][8 nf][64][8]
    const float* __restrict__ b2,
    unsigned short* __restrict__ msgout)
{
  constexpr int H1ST = 264;                  // ushort stride, breaks pow2 banks
  __shared__ unsigned short h1s[32 * H1ST];  // 16.9 KB

  const int tid  = threadIdx.x;
  const int wave = tid >> 6;
  const int lane = tid & 63;
  const int c    = lane & 15;
  const int quad = lane >> 4;

  // ---- one-time: register-resident weight slices ----
  const bf16x8* W1f = (const bf16x8*)W1p;
  const bf16x8* W2f = (const bf16x8*)W2p;
  bf16x8 w1r[32];
  #pragma unroll
  for (int ks = 0; ks < 8; ++ks)
    #pragma unroll
    for (int i = 0; i < 4; ++i)
      w1r[ks * 4 + i] = W1f[(ks * 16 + wave * 4 + i) * 64 + lane];
  bf16x8 w2r[16];
  #pragma unroll
  for (int ks = 0; ks < 8; ++ks)
    #pragma unroll
    for (int i = 0; i < 2; ++i)
      w2r[ks * 2 + i] = W2f[(ks * 8 + wave * 2 + i) * 64 + lane];

  float4 b1v[4];
  #pragma unroll
  for (int i = 0; i < 4; ++i)
    b1v[i] = *(const float4*)(b1 + (wave * 4 + i) * 16 + quad * 4);
  float4 b2v[2];
  #pragma unroll
  for (int i = 0; i < 2; ++i)
    b2v[i] = *(const float4*)(b2 + (wave * 2 + i) * 16 + quad * 4);

  const int nTiles = NUM_M / 32;             // 6250 exact
  int tile = blockIdx.x;
  if (tile >= nTiles) return;

  // prologue: indices + acts for first tile
  bf16x8 actA[8], actB[8];
  {
    int mA = order[tile * 32 + c];
    int mB = order[tile * 32 + 16 + c];
    int fA = first[mA], sA = second[mA];
    int fB = first[mB], sB = second[mB];
    const unsigned short* fra = lsb + (size_t)fA * DIM + quad * 8;
    const unsigned short* sra = lsb + (size_t)sA * DIM + quad * 8;
    const unsigned short* frb = lsb + (size_t)fB * DIM + quad * 8;
    const unsigned short* srb = lsb + (size_t)sB * DIM + quad * 8;
    #pragma unroll
    for (int ks = 0; ks < 4; ++ks) {
      actA[ks]     = *(const bf16x8*)(fra + ks * 32);
      actA[4 + ks] = *(const bf16x8*)(sra + ks * 32);
      actB[ks]     = *(const bf16x8*)(frb + ks * 32);
      actB[4 + ks] = *(const bf16x8*)(srb + ks * 32);
    }
  }

  while (true) {
    const int m0 = tile * 32;
    const int next = tile + gridDim.x;
    const bool have_next = (next < nTiles);   // block-uniform

    // prefetch next tile's indices (resolve during layer-1 MFMA)
    int nfA = 0, nsA = 0, nfB = 0, nsB = 0;
    if (have_next) {
      int nmA = order[next * 32 + c];
      int nmB = order[next * 32 + 16 + c];
      nfA = first[nmA]; nsA = second[nmA];
      nfB = first[nmB]; nsB = second[nmB];
    }

    // ---- layer 1: this wave's 4 nf frags, both sets ----
    f32x4 accA[4], accB[4];
    #pragma unroll
    for (int i = 0; i < 4; ++i) { accA[i] = (f32x4)(0.f); accB[i] = (f32x4)(0.f); }
    #pragma unroll
    for (int ks = 0; ks < 8; ++ks) {
      #pragma unroll
      for (int i = 0; i < 4; ++i) {
        accA[i] = MFMA(w1r[ks * 4 + i], actA[ks], accA[i]);
        accB[i] = MFMA(w1r[ks * 4 + i], actB[ks], accB[i]);
      }
    }

    // prefetch next tile's act rows (resolve during epilogue/layer-2/stores)
    bf16x8 nactA[8], nactB[8];
    if (have_next) {
      const unsigned short* fra = lsb + (size_t)nfA * DIM + quad * 8;
      const unsigned short* sra = lsb + (size_t)nsA * DIM + quad * 8;
      const unsigned short* frb = lsb + (size_t)nfB * DIM + quad * 8;
      const unsigned short* srb = lsb + (size_t)nsB * DIM + quad * 8;
      #pragma unroll
      for (int ks = 0; ks < 4; ++ks) {
        nactA[ks]     = *(const bf16x8*)(fra + ks * 32);
        nactA[4 + ks] = *(const bf16x8*)(sra + ks * 32);
        nactB[ks]     = *(const bf16x8*)(frb + ks * 32);
        nactB[4 + ks] = *(const bf16x8*)(srb + ks * 32);
      }
    }

    // bias+relu -> bf16 -> block-shared h1 tile (this wave's 64-col slice)
    #pragma unroll
    for (int i = 0; i < 4; ++i) {
      int n0 = (wave * 4 + i) * 16 + quad * 4;
      ushort4 pa, pb;
      pa.x = f2bf(relu_(accA[i][0] + b1v[i].x));
      pa.y = f2bf(relu_(accA[i][1] + b1v[i].y));
      pa.z = f2bf(relu_(accA[i][2] + b1v[i].z));
      pa.w = f2bf(relu_(accA[i][3] + b1v[i].w));
      pb.x = f2bf(relu_(accB[i][0] + b1v[i].x));
      pb.y = f2bf(relu_(accB[i][1] + b1v[i].y));
      pb.z = f2bf(relu_(accB[i][2] + b1v[i].z));
      pb.w = f2bf(relu_(accB[i][3] + b1v[i].w));
      *(ushort4*)&h1s[(c)      * H1ST + n0] = pa;
      *(ushort4*)&h1s[(16 + c) * H1ST + n0] = pb;
    }
    __syncthreads();

    // ---- layer 2: this wave's 2 nf frags, K=256 from shared h1 ----
    f32x4 a2A[2], a2B[2];
    #pragma unroll
    for (int i = 0; i < 2; ++i) { a2A[i] = (f32x4)(0.f); a2B[i] = (f32x4)(0.f); }
    #pragma unroll
    for (int ks2 = 0; ks2 < 8; ++ks2) {
      bf16x8 bA = *(const bf16x8*)&h1s[(c)      * H1ST + ks2 * 32 + quad * 8];
      bf16x8 bB = *(const bf16x8*)&h1s[(16 + c) * H1ST + ks2 * 32 + quad * 8];
      #pragma unroll
      for (int i = 0; i < 2; ++i) {
        a2A[i] = MFMA(w2r[ks2 * 2 + i], bA, a2A[i]);
        a2B[i] = MFMA(w2r[ks2 * 2 + i], bB, a2B[i]);
      }
    }

    // epilogue: write this wave's 32-col slice of both sets
    #pragma unroll
    for (int i = 0; i < 2; ++i) {
      int n0 = (wave * 2 + i) * 16 + quad * 4;
      ushort4 pa, pb;
      pa.x = f2bf(relu_(a2A[i][0] + b2v[i].x));
      pa.y = f2bf(relu_(a2A[i][1] + b2v[i].y));
      pa.z = f2bf(relu_(a2A[i][2] + b2v[i].z));
      pa.w = f2bf(relu_(a2A[i][3] + b2v[i].w));
      pb.x = f2bf(relu_(a2B[i][0] + b2v[i].x));
      pb.y = f2bf(relu_(a2B[i][1] + b2v[i].y));
      pb.z = f2bf(relu_(a2B[i][2] + b2v[i].z));
      pb.w = f2bf(relu_(a2B[i][3] + b2v[i].w));
      *(ushort4*)(msgout + (size_t)(m0 + c) * DIM + n0)      = pa;
      *(ushort4*)(msgout + (size_t)(m0 + 16 + c) * DIM + n0) = pb;
    }
    __syncthreads();   // h1s reused next tile

    if (!have_next) break;
    tile = next;
    #pragma unroll
    for (int i = 0; i < 8; ++i) { actA[i] = nactA[i]; actB[i] = nactB[i]; }
  }
}

// ---------------- GRU: bf16-carried h only; batched row stores; 2x seg-sum ILP ----------------
__global__ __launch_bounds__(256) void gru_kernel(
    const unsigned short* __restrict__ msgb,  // [M,128] bf16, permuted (CSR row order)
    const int* __restrict__ rowptr,           // [E+1]
    unsigned short* __restrict__ lsb,         // h bf16, in-place (the only master)
    const unsigned short* __restrict__ Wzrp,  // packed [8][16][64][8]
    const unsigned short* __restrict__ Wkhp,  // packed [4][8][64][8]
    const unsigned short* __restrict__ Wrhp,  // packed [4][8][64][8]
    const float* __restrict__ gb)             // [2][384]
{
  const int tid  = threadIdx.x;
  const int wave = tid >> 6;
  const int lane = tid & 63;
  const int c    = lane & 15;
  const int quad = lane >> 4;
  const int e0   = blockIdx.x * 64 + wave * 16;
  const int e    = e0 + c;
  const int ec   = min(e, NUM_E - 1);

  // fused segment-sum, 2 rows/iter (dual accumulators for MLP)
  float xacc0[4][8], xacc1[4][8];
  #pragma unroll
  for (int ks = 0; ks < 4; ++ks)
    #pragma unroll
    for (int j = 0; j < 8; ++j) { xacc0[ks][j] = 0.f; xacc1[ks][j] = 0.f; }

  const int rs = rowptr[ec], re = rowptr[ec + 1];
  int p = rs;
  for (; p + 1 < re; p += 2) {
    const unsigned short* mr0 = msgb + (size_t)p * DIM + quad * 8;
    const unsigned short* mr1 = msgb + (size_t)(p + 1) * DIM + quad * 8;
    #pragma unroll
    for (int ks = 0; ks < 4; ++ks) {
      bf16x8 v0 = *(const bf16x8*)(mr0 + ks * 32);
      bf16x8 v1 = *(const bf16x8*)(mr1 + ks * 32);
      #pragma unroll
      for (int j = 0; j < 8; ++j) {
        xacc0[ks][j] += bf2f((unsigned short)v0[j]);
        xacc1[ks][j] += bf2f((unsigned short)v1[j]);
      }
    }
  }
  if (p < re) {
    const unsigned short* mr0 = msgb + (size_t)p * DIM + quad * 8;
    #pragma unroll
    for (int ks = 0; ks < 4; ++ks) {
      bf16x8 v0 = *(const bf16x8*)(mr0 + ks * 32);
      #pragma unroll
      for (int j = 0; j < 8; ++j) xacc0[ks][j] += bf2f((unsigned short)v0[j]);
    }
  }

  bf16x8 xf[4], hf[4];
  #pragma unroll
  for (int ks = 0; ks < 4; ++ks) {
    bf16x8 v;
    #pragma unroll
    for (int j = 0; j < 8; ++j) v[j] = (short)f2bf(xacc0[ks][j] + xacc1[ks][j]);
    xf[ks] = v;
  }
  const unsigned short* hrow = lsb + (size_t)ec * DIM + quad * 8;
  #pragma unroll
  for (int ks = 0; ks < 4; ++ks) hf[ks] = *(const bf16x8*)(hrow + ks * 32);

  const bf16x8* Wzrf = (const bf16x8*)Wzrp;
  const bf16x8* Wkhf = (const bf16x8*)Wkhp;
  const bf16x8* Wrhf = (const bf16x8*)Wrhp;
  const float4* gbv  = (const float4*)gb;

  ushort4 pks[8];                            // batched row stores

  // per n-column: only 4 live accumulators -> low VGPR, high occupancy
  #pragma unroll 1
  for (int nf = 0; nf < 8; ++nf) {
    f32x4 az = (f32x4)(0.f), ar = (f32x4)(0.f);
    f32x4 axh = (f32x4)(0.f), ahh = (f32x4)(0.f);
    #pragma unroll
    for (int ks = 0; ks < 8; ++ks) {
      bf16x8 bb = (ks < 4) ? xf[ks] : hf[ks - 4];
      az = MFMA(Wzrf[(ks * 16 + nf) * 64 + lane], bb, az);
      ar = MFMA(Wzrf[(ks * 16 + nf + 8) * 64 + lane], bb, ar);
    }
    #pragma unroll
    for (int ks = 0; ks < 4; ++ks) {
      axh = MFMA(Wkhf[(ks * 8 + nf) * 64 + lane], xf[ks], axh);
      ahh = MFMA(Wrhf[(ks * 8 + nf) * 64 + lane], hf[ks], ahh);
    }

    int n0 = nf * 16 + quad * 4;
    int q4 = nf * 4 + quad;
    float4 b0z = gbv[q4],       b0r = gbv[32 + q4],  b0h = gbv[64 + q4];
    float4 b1z = gbv[96 + q4],  b1r = gbv[128 + q4], b1h = gbv[160 + q4];
    // hold = carried bf16 h (row already hot in L1 from the hf reads)
    ushort4 hraw = *(const ushort4*)(lsb + (size_t)ec * DIM + n0);
    float ho[4] = { bf2f(hraw.x), bf2f(hraw.y), bf2f(hraw.z), bf2f(hraw.w) };
    const float* pz  = (const float*)&az;
    const float* pr  = (const float*)&ar;
    const float* pxh = (const float*)&axh;
    const float* phh = (const float*)&ahh;
    const float* b0za = (const float*)&b0z; const float* b0ra = (const float*)&b0r;
    const float* b0ha = (const float*)&b0h; const float* b1za = (const float*)&b1z;
    const float* b1ra = (const float*)&b1r; const float* b1ha = (const float*)&b1h;
    ushort4 pk;
    {
      float z  = sigmoidf_(pz[0] + b0za[0] + b1za[0]);
      float r  = sigmoidf_(pr[0] + b0ra[0] + b1ra[0]);
      float hc = tanhf_(pxh[0] + b0ha[0] + r * (phh[0] + b1ha[0]));
      pk.x = f2bf(z * ho[0] + (1.f - z) * hc);
    }
    {
      float z  = sigmoidf_(pz[1] + b0za[1] + b1za[1]);
      float r  = sigmoidf_(pr[1] + b0ra[1] + b1ra[1]);
      float hc = tanhf_(pxh[1] + b0ha[1] + r * (phh[1] + b1ha[1]));
      pk.y = f2bf(z * ho[1] + (1.f - z) * hc);
    }
    {
      float z  = sigmoidf_(pz[2] + b0za[2] + b1za[2]);
      float r  = sigmoidf_(pr[2] + b0ra[2] + b1ra[2]);
      float hc = tanhf_(pxh[2] + b0ha[2] + r * (phh[2] + b1ha[2]));
      pk.z = f2bf(z * ho[2] + (1.f - z) * hc);
    }
    {
      float z  = sigmoidf_(pz[3] + b0za[3] + b1za[3]);
      float r  = sigmoidf_(pr[3] + b0ra[3] + b1ra[3]);
      float hc = tanhf_(pxh[3] + b0ha[3] + r * (phh[3] + b1ha[3]));
      pk.w = f2bf(z * ho[3] + (1.f - z) * hc);
    }
    pks[nf] = pk;
  }

  // batched stores: the row's 8 chunks written back-to-back -> lines complete fast
  if (e < NUM_E) {
    unsigned short* dst = lsb + (size_t)e * DIM + quad * 4;
    #pragma unroll
    for (int nf = 0; nf < 8; ++nf)
      *(ushort4*)(dst + nf * 16) = pks[nf];
  }
}

// ---------------- graph segment-sum (sorted ids; reads bf16 h, fp32 accum) ----------------
__global__ __launch_bounds__(256) void graph_sum_kernel(
    const unsigned short* __restrict__ lsb, const int* __restrict__ gids,
    float* __restrict__ gs) {
  const int t = threadIdx.x;
  const int d = t & 127;
  const int half = t >> 7;
  const int e0 = blockIdx.x * GS_ER;
  const int e1 = min(e0 + GS_ER, NUM_E);
  float acc = 0.f;
  int cur = -1;
  for (int e = e0 + half; e < e1; e += 2) {
    int g = gids[e];
    if (g != cur) {
      if (cur >= 0) atomicAdd(&gs[cur * DIM + d], acc);
      acc = 0.f;
      cur = g;
    }
    acc += bf2f(lsb[(size_t)e * DIM + d]);
  }
  if (cur >= 0) atomicAdd(&gs[cur * DIM + d], acc);
}

// ---------------- fused readout: 3 layers in one kernel ----------------
__global__ __launch_bounds__(256) void readout_kernel(
    const float* __restrict__ gs,
    const float* __restrict__ rW1, const float* __restrict__ rb1,
    const float* __restrict__ rW2, const float* __restrict__ rb2,
    const float* __restrict__ rW3, const float* __restrict__ rb3,
    float* __restrict__ out) {
  __shared__ float shg[DIM];
  __shared__ float sh1[HID];
  __shared__ float red[HID];
  int g = blockIdx.x, c = threadIdx.x;
  if (c < DIM) shg[c] = gs[g * DIM + c];
  __syncthreads();
  float s = rb1[c];
  for (int k = 0; k < DIM; ++k) s += shg[k] * rW1[k * HID + c];
  sh1[c] = relu_(s);
  __syncthreads();
  s = rb2[c];
  for (int k = 0; k < HID; ++k) s += sh1[k] * rW2[k * HID + c];
  red[c] = relu_(s) * rW3[c];
  __syncthreads();
  for (int off = 128; off > 0; off >>= 1) {
    if (c < off) red[c] += red[c + off];
    __syncthreads();
  }
  if (c == 0) out[g] = red[0] + rb3[0];
}

extern "C" void kernel_launch(void* const* d_in, const int* in_sizes, int n_in,
                              void* d_out, int out_size, void* d_ws, size_t ws_size,
                              hipStream_t stream) {
  float* ls          = (float*)d_in[0];        // fp32 link_state (read-only here)
  const int* first   = (const int*)d_in[1];
  const int* second  = (const int*)d_in[2];
  const int* gids    = (const int*)d_in[3];
  const float* mW1   = (const float*)d_in[5];
  const float* mb1   = (const float*)d_in[6];
  const float* mW2   = (const float*)d_in[7];
  const float* mb2   = (const float*)d_in[8];
  const float* gk    = (const float*)d_in[9];
  const float* gr    = (const float*)d_in[10];
  const float* gb    = (const float*)d_in[11];
  const float* rW1   = (const float*)d_in[12];
  const float* rb1   = (const float*)d_in[13];
  const float* rW2   = (const float*)d_in[14];
  const float* rb2   = (const float*)d_in[15];
  const float* rW3   = (const float*)d_in[16];
  const float* rb3   = (const float*)d_in[17];
  float* out = (float*)d_out;

  // workspace layout
  char* w = (char*)d_ws;
  unsigned short* msgb = (unsigned short*)w;    w += (size_t)NUM_M * DIM * 2;   // 51.2 MB
  unsigned short* lsb  = (unsigned short*)w;    w += (size_t)NUM_E * DIM * 2;   // 25.6 MB
  float* gs    = (float*)w;                     w += NG * DIM * 4;
  int* counts  = (int*)w;                       w += NUM_E * 4;
  int* cursor  = (int*)w;                       w += NUM_E * 4;   // adjacent to counts
  int* rowptr  = (int*)w;                       w += (NUM_E + 4) * 4;
  int* order   = (int*)w;                       w += NUM_M * 4;
  int* partials= (int*)w;                       w += NB_SCAN * 4;
  int* basep   = (int*)w;                       w += NB_SCAN * 4;
  unsigned short* W1p  = (unsigned short*)w;    w += 256 * 256 * 2;
  unsigned short* W2p  = (unsigned short*)w;    w += 256 * 128 * 2;
  unsigned short* Wzrp = (unsigned short*)w;    w += 256 * 256 * 2;
  unsigned short* Wkhp = (unsigned short*)w;    w += 128 * 128 * 2;
  unsigned short* Wrhp = (unsigned short*)w;    w += 128 * 128 * 2;

  // prep: bf16 link_state + all weight packs, one launch
  const int n4 = NUM_E * DIM / 4;
  prep_kernel<<<(n4 + 255) / 256, 256, 0, stream>>>(
      (const float4*)ls, (ushort4*)lsb, n4, mW1, mW2, gk, gr,
      W1p, W2p, Wzrp, Wkhp, Wrhp);

  // CSR build (parallel 3-kernel scan)
  hipMemsetAsync(counts, 0, 2 * (size_t)NUM_E * 4, stream);   // counts + cursor
  hist_kernel<<<(NUM_M + 255) / 256, 256, 0, stream>>>(second, counts, (float4*)gs);
  scan1_kernel<<<NB_SCAN, 256, 0, stream>>>(counts, partials);
  scan2_kernel<<<1, 64, 0, stream>>>(partials, basep, rowptr);
  scan3_kernel<<<NB_SCAN, 256, 0, stream>>>(counts, basep, rowptr);
  scatter_kernel<<<(NUM_M + 255) / 256, 256, 0, stream>>>(second, rowptr, cursor, order);

  const int gruBlocks = (NUM_E + 63) / 64;
  for (int t = 0; t < TITER; ++t) {
    msg_kernel<<<512, 256, 0, stream>>>(lsb, first, second, order, W1p, mb1, W2p, mb2, msgb);
    gru_kernel<<<gruBlocks, 256, 0, stream>>>(msgb, rowptr, lsb, Wzrp, Wkhp, Wrhp, gb);
  }
  graph_sum_kernel<<<(NUM_E + GS_ER - 1) / GS_ER, 256, 0, stream>>>(lsb, gids, gs);
  readout_kernel<<<NG, HID, 0, stream>>>(gs, rW1, rb1, rW2, rb2, rW3, rb3, out);
}

// Round 14
// 681.717 us; speedup vs baseline: 1.0561x; 1.0561x over previous
//
#include <hip/hip_runtime.h>

#define NUM_E 100000
#define NUM_M 200000
#define DIM   128
#define HID   256
#define NG    64
#define TITER 3
#define NB_SCAN 98   // ceil(NUM_E/1024)
#define GS_ER 128    // edges per block in graph_sum

typedef __attribute__((ext_vector_type(8))) short bf16x8;
typedef __attribute__((ext_vector_type(4))) float f32x4;

__device__ __forceinline__ unsigned short f2bf(float f) {
  unsigned u = __float_as_uint(f);
  u += 0x7FFF + ((u >> 16) & 1);          // RNE
  return (unsigned short)(u >> 16);
}
__device__ __forceinline__ float bf2f(unsigned short h) {
  return __uint_as_float(((unsigned)h) << 16);
}
__device__ __forceinline__ float sigmoidf_(float v) {
  return 1.f / (1.f + __expf(-v));
}
__device__ __forceinline__ float tanhf_(float u) {
  u = fminf(fmaxf(u, -15.f), 15.f);
  float ex = __expf(-2.f * u);
  return (1.f - ex) / (1.f + ex);
}
__device__ __forceinline__ float relu_(float v) { return fmaxf(v, 0.f); }

#define MFMA(a, b, c) __builtin_amdgcn_mfma_f32_16x16x32_bf16((a), (b), (c), 0, 0, 0)

// ---------------- CSR: histogram (also zeroes gs) ----------------
__global__ void hist_kernel(const int* __restrict__ second, int* __restrict__ counts,
                            float4* __restrict__ gs4) {
  int m = blockIdx.x * blockDim.x + threadIdx.x;
  if (m < NG * DIM / 4) gs4[m] = make_float4(0.f, 0.f, 0.f, 0.f);
  if (m < NUM_M) atomicAdd(&counts[second[m]], 1);
}

// ---------------- 3-kernel parallel scan (coalesced; R10-proven) ----------------
__global__ __launch_bounds__(256) void scan1_kernel(const int* __restrict__ counts,
                                                    int* __restrict__ partials) {
  __shared__ int sh[256];
  int b = blockIdx.x, t = threadIdx.x;
  int i0 = b * 1024 + t * 4;
  int c0 = (i0 + 0 < NUM_E) ? counts[i0 + 0] : 0;
  int c1 = (i0 + 1 < NUM_E) ? counts[i0 + 1] : 0;
  int c2 = (i0 + 2 < NUM_E) ? counts[i0 + 2] : 0;
  int c3 = (i0 + 3 < NUM_E) ? counts[i0 + 3] : 0;
  int tsum = c0 + c1 + c2 + c3;
  sh[t] = tsum;
  __syncthreads();
  for (int off = 1; off < 256; off <<= 1) {
    int v = (t >= off) ? sh[t - off] : 0;
    __syncthreads();
    sh[t] += v;
    __syncthreads();
  }
  if (t == 255) partials[b] = sh[255];
}

__global__ void scan2_kernel(const int* __restrict__ partials, int* __restrict__ base,
                             int* __restrict__ rowptr) {
  if (threadIdx.x == 0) {
    int run = 0;
    for (int b = 0; b < NB_SCAN; ++b) { base[b] = run; run += partials[b]; }
    rowptr[NUM_E] = NUM_M;
  }
}

__global__ __launch_bounds__(256) void scan3_kernel(const int* __restrict__ counts,
                                                    const int* __restrict__ base,
                                                    int* __restrict__ rowptr) {
  __shared__ int sh[256];
  int b = blockIdx.x, t = threadIdx.x;
  int i0 = b * 1024 + t * 4;
  int c0 = (i0 + 0 < NUM_E) ? counts[i0 + 0] : 0;
  int c1 = (i0 + 1 < NUM_E) ? counts[i0 + 1] : 0;
  int c2 = (i0 + 2 < NUM_E) ? counts[i0 + 2] : 0;
  int c3 = (i0 + 3 < NUM_E) ? counts[i0 + 3] : 0;
  int tsum = c0 + c1 + c2 + c3;
  sh[t] = tsum;
  __syncthreads();
  for (int off = 1; off < 256; off <<= 1) {
    int v = (t >= off) ? sh[t - off] : 0;
    __syncthreads();
    sh[t] += v;
    __syncthreads();
  }
  int p = base[b] + (sh[t] - tsum);
  if (i0 + 0 < NUM_E) rowptr[i0 + 0] = p;
  if (i0 + 1 < NUM_E) rowptr[i0 + 1] = p + c0;
  if (i0 + 2 < NUM_E) rowptr[i0 + 2] = p + c0 + c1;
  if (i0 + 3 < NUM_E) rowptr[i0 + 3] = p + c0 + c1 + c2;
}

__global__ void scatter_kernel(const int* __restrict__ second,
                               const int* __restrict__ rowptr,
                               int* __restrict__ cursor, int* __restrict__ order) {
  int m = blockIdx.x * blockDim.x + threadIdx.x;
  if (m < NUM_M) {
    int e = second[m];
    int pos = atomicAdd(&cursor[e], 1);
    int idx = rowptr[e] + pos;
    if (idx < rowptr[e + 1]) order[idx] = m;   // guard: rocprof replay re-runs w/o re-zero
  }
}

// ---------------- fused prep: fp32->bf16 cvt + all weight packs ----------------
__device__ __forceinline__ void pack_range(
    const float* __restrict__ srcA, const float* __restrict__ srcB, int KrowsA,
    int N, int src_ld, int col_off, unsigned short* __restrict__ dst, int idx) {
  int l = idx & 63;
  int t = idx >> 6;
  int NF = N / 16;
  int nf = t % NF;
  int ks = t / NF;
  int n = nf * 16 + (l & 15) + col_off;
  int k0 = ks * 32 + (l >> 4) * 8;
  unsigned short o[8];
  #pragma unroll
  for (int j = 0; j < 8; ++j) {
    int k = k0 + j;
    const float* src = (k < KrowsA) ? (srcA + (size_t)k * src_ld)
                                    : (srcB + (size_t)(k - KrowsA) * src_ld);
    o[j] = f2bf(src[n]);
  }
  ushort4* d = (ushort4*)(dst + (size_t)idx * 8);
  d[0] = make_ushort4(o[0], o[1], o[2], o[3]);
  d[1] = make_ushort4(o[4], o[5], o[6], o[7]);
}

// grid covers n4 = NUM_E*DIM/4 threads; ids < 24576 also pack weights
__global__ __launch_bounds__(256) void prep_kernel(
    const float4* __restrict__ ls4, ushort4* __restrict__ lsb4, int n4,
    const float* __restrict__ mW1, const float* __restrict__ mW2,
    const float* __restrict__ gk,  const float* __restrict__ gr,
    unsigned short* __restrict__ W1p,  unsigned short* __restrict__ W2p,
    unsigned short* __restrict__ Wzrp, unsigned short* __restrict__ Wkhp,
    unsigned short* __restrict__ Wrhp) {
  int i = blockIdx.x * 256 + threadIdx.x;
  if (i < n4) {
    float4 v = ls4[i];
    ushort4 o;
    o.x = f2bf(v.x); o.y = f2bf(v.y); o.z = f2bf(v.z); o.w = f2bf(v.w);
    lsb4[i] = o;
  }
  if      (i < 8192)  pack_range(mW1, mW1, 256, 256, 256, 0,   W1p,  i);
  else if (i < 12288) pack_range(mW2, mW2, 256, 128, 128, 0,   W2p,  i - 8192);
  else if (i < 20480) pack_range(gk,  gr,  128, 256, 384, 0,   Wzrp, i - 12288);
  else if (i < 22528) pack_range(gk,  gk,  128, 128, 384, 256, Wkhp, i - 20480);
  else if (i < 24576) pack_range(gr,  gr,  128, 128, 384, 256, Wrhp, i - 22528);
}

// ---------------- message MLP: persistent weights + pipelined gather ----------------
// R9 structure + ping-pong h1s: one barrier per tile instead of two.
__global__ __launch_bounds__(256, 1) void msg_kernel(
    const unsigned short* __restrict__ lsb,   // [E,128] bf16
    const int* __restrict__ first, const int* __restrict__ second,
    const int* __restrict__ order,            // [M] permutation
    const unsigned short* __restrict__ W1p,   // packed [8 ks][16 nf][64][8]
    const float* __restrict__ b1,
    const unsigned short* __restrict__ W2p,   // packed [8 ks][8 nf][64][8]
    const float* __restrict__ b2,
    unsigned short* __restrict__ msgout)
{
  constexpr int H1ST = 264;                  // ushort stride, breaks pow2 banks
  __shared__ unsigned short h1s[2][32 * H1ST];  // 33.8 KB ping-pong

  const int tid  = threadIdx.x;
  const int wave = tid >> 6;
  const int lane = tid & 63;
  const int c    = lane & 15;
  const int quad = lane >> 4;

  // ---- one-time: register-resident weight slices ----
  const bf16x8* W1f = (const bf16x8*)W1p;
  const bf16x8* W2f = (const bf16x8*)W2p;
  bf16x8 w1r[32];
  #pragma unroll
  for (int ks = 0; ks < 8; ++ks)
    #pragma unroll
    for (int i = 0; i < 4; ++i)
      w1r[ks * 4 + i] = W1f[(ks * 16 + wave * 4 + i) * 64 + lane];
  bf16x8 w2r[16];
  #pragma unroll
  for (int ks = 0; ks < 8; ++ks)
    #pragma unroll
    for (int i = 0; i < 2; ++i)
      w2r[ks * 2 + i] = W2f[(ks * 8 + wave * 2 + i) * 64 + lane];

  float4 b1v[4];
  #pragma unroll
  for (int i = 0; i < 4; ++i)
    b1v[i] = *(const float4*)(b1 + (wave * 4 + i) * 16 + quad * 4);
  float4 b2v[2];
  #pragma unroll
  for (int i = 0; i < 2; ++i)
    b2v[i] = *(const float4*)(b2 + (wave * 2 + i) * 16 + quad * 4);

  const int nTiles = NUM_M / 32;             // 6250 exact
  int tile = blockIdx.x;
  if (tile >= nTiles) return;
  int parity = 0;

  // prologue: indices + acts for first tile
  bf16x8 actA[8], actB[8];
  {
    int mA = order[tile * 32 + c];
    int mB = order[tile * 32 + 16 + c];
    int fA = first[mA], sA = second[mA];
    int fB = first[mB], sB = second[mB];
    const unsigned short* fra = lsb + (size_t)fA * DIM + quad * 8;
    const unsigned short* sra = lsb + (size_t)sA * DIM + quad * 8;
    const unsigned short* frb = lsb + (size_t)fB * DIM + quad * 8;
    const unsigned short* srb = lsb + (size_t)sB * DIM + quad * 8;
    #pragma unroll
    for (int ks = 0; ks < 4; ++ks) {
      actA[ks]     = *(const bf16x8*)(fra + ks * 32);
      actA[4 + ks] = *(const bf16x8*)(sra + ks * 32);
      actB[ks]     = *(const bf16x8*)(frb + ks * 32);
      actB[4 + ks] = *(const bf16x8*)(srb + ks * 32);
    }
  }

  while (true) {
    const int m0 = tile * 32;
    const int next = tile + gridDim.x;
    const bool have_next = (next < nTiles);   // block-uniform

    // prefetch next tile's indices (resolve during layer-1 MFMA)
    int nfA = 0, nsA = 0, nfB = 0, nsB = 0;
    if (have_next) {
      int nmA = order[next * 32 + c];
      int nmB = order[next * 32 + 16 + c];
      nfA = first[nmA]; nsA = second[nmA];
      nfB = first[nmB]; nsB = second[nmB];
    }

    // ---- layer 1: this wave's 4 nf frags, both sets ----
    f32x4 accA[4], accB[4];
    #pragma unroll
    for (int i = 0; i < 4; ++i) { accA[i] = (f32x4)(0.f); accB[i] = (f32x4)(0.f); }
    #pragma unroll
    for (int ks = 0; ks < 8; ++ks) {
      #pragma unroll
      for (int i = 0; i < 4; ++i) {
        accA[i] = MFMA(w1r[ks * 4 + i], actA[ks], accA[i]);
        accB[i] = MFMA(w1r[ks * 4 + i], actB[ks], accB[i]);
      }
    }

    // prefetch next tile's act rows (resolve during epilogue/layer-2/stores)
    bf16x8 nactA[8], nactB[8];
    if (have_next) {
      const unsigned short* fra = lsb + (size_t)nfA * DIM + quad * 8;
      const unsigned short* sra = lsb + (size_t)nsA * DIM + quad * 8;
      const unsigned short* frb = lsb + (size_t)nfB * DIM + quad * 8;
      const unsigned short* srb = lsb + (size_t)nsB * DIM + quad * 8;
      #pragma unroll
      for (int ks = 0; ks < 4; ++ks) {
        nactA[ks]     = *(const bf16x8*)(fra + ks * 32);
        nactA[4 + ks] = *(const bf16x8*)(sra + ks * 32);
        nactB[ks]     = *(const bf16x8*)(frb + ks * 32);
        nactB[4 + ks] = *(const bf16x8*)(srb + ks * 32);
      }
    }

    // bias+relu -> bf16 -> h1s[parity] (this wave's 64-col slice)
    unsigned short* hb = &h1s[parity][0];
    #pragma unroll
    for (int i = 0; i < 4; ++i) {
      int n0 = (wave * 4 + i) * 16 + quad * 4;
      ushort4 pa, pb;
      pa.x = f2bf(relu_(accA[i][0] + b1v[i].x));
      pa.y = f2bf(relu_(accA[i][1] + b1v[i].y));
      pa.z = f2bf(relu_(accA[i][2] + b1v[i].z));
      pa.w = f2bf(relu_(accA[i][3] + b1v[i].w));
      pb.x = f2bf(relu_(accB[i][0] + b1v[i].x));
      pb.y = f2bf(relu_(accB[i][1] + b1v[i].y));
      pb.z = f2bf(relu_(accB[i][2] + b1v[i].z));
      pb.w = f2bf(relu_(accB[i][3] + b1v[i].w));
      *(ushort4*)&hb[(c)      * H1ST + n0] = pa;
      *(ushort4*)&hb[(16 + c) * H1ST + n0] = pb;
    }
    __syncthreads();                         // the ONLY barrier per tile

    // ---- layer 2: this wave's 2 nf frags, K=256 from shared h1 ----
    f32x4 a2A[2], a2B[2];
    #pragma unroll
    for (int i = 0; i < 2; ++i) { a2A[i] = (f32x4)(0.f); a2B[i] = (f32x4)(0.f); }
    #pragma unroll
    for (int ks2 = 0; ks2 < 8; ++ks2) {
      bf16x8 bA = *(const bf16x8*)&hb[(c)      * H1ST + ks2 * 32 + quad * 8];
      bf16x8 bB = *(const bf16x8*)&hb[(16 + c) * H1ST + ks2 * 32 + quad * 8];
      #pragma unroll
      for (int i = 0; i < 2; ++i) {
        a2A[i] = MFMA(w2r[ks2 * 2 + i], bA, a2A[i]);
        a2B[i] = MFMA(w2r[ks2 * 2 + i], bB, a2B[i]);
      }
    }

    // epilogue: write this wave's 32-col slice of both sets
    #pragma unroll
    for (int i = 0; i < 2; ++i) {
      int n0 = (wave * 2 + i) * 16 + quad * 4;
      ushort4 pa, pb;
      pa.x = f2bf(relu_(a2A[i][0] + b2v[i].x));
      pa.y = f2bf(relu_(a2A[i][1] + b2v[i].y));
      pa.z = f2bf(relu_(a2A[i][2] + b2v[i].z));
      pa.w = f2bf(relu_(a2A[i][3] + b2v[i].w));
      pb.x = f2bf(relu_(a2B[i][0] + b2v[i].x));
      pb.y = f2bf(relu_(a2B[i][1] + b2v[i].y));
      pb.z = f2bf(relu_(a2B[i][2] + b2v[i].z));
      pb.w = f2bf(relu_(a2B[i][3] + b2v[i].w));
      *(ushort4*)(msgout + (size_t)(m0 + c) * DIM + n0)      = pa;
      *(ushort4*)(msgout + (size_t)(m0 + 16 + c) * DIM + n0) = pb;
    }

    if (!have_next) break;
    tile = next;
    parity ^= 1;                             // next tile writes the other buffer
    #pragma unroll
    for (int i = 0; i < 8; ++i) { actA[i] = nactA[i]; actB[i] = nactB[i]; }
  }
}

// ---------------- GRU (R12 body): bf16-carried h, interleaved stores ----------------
__global__ __launch_bounds__(256) void gru_kernel(
    const unsigned short* __restrict__ msgb,  // [M,128] bf16, permuted (CSR row order)
    const int* __restrict__ rowptr,           // [E+1]
    unsigned short* __restrict__ lsb,         // h bf16, in-place (the only master)
    const unsigned short* __restrict__ Wzrp,  // packed [8][16][64][8]
    const unsigned short* __restrict__ Wkhp,  // packed [4][8][64][8]
    const unsigned short* __restrict__ Wrhp,  // packed [4][8][64][8]
    const float* __restrict__ gb)             // [2][384]
{
  const int tid  = threadIdx.x;
  const int wave = tid >> 6;
  const int lane = tid & 63;
  const int c    = lane & 15;
  const int quad = lane >> 4;
  const int e0   = blockIdx.x * 64 + wave * 16;
  const int e    = e0 + c;
  const int ec   = min(e, NUM_E - 1);

  // fused segment-sum: rows rowptr[ec]..rowptr[ec+1] are CONTIGUOUS in msgb
  float xacc[4][8];
  #pragma unroll
  for (int ks = 0; ks < 4; ++ks)
    #pragma unroll
    for (int j = 0; j < 8; ++j) xacc[ks][j] = 0.f;

  const int rs = rowptr[ec], re = rowptr[ec + 1];
  for (int p = rs; p < re; ++p) {
    const unsigned short* mr = msgb + (size_t)p * DIM + quad * 8;
    #pragma unroll
    for (int ks = 0; ks < 4; ++ks) {
      bf16x8 v = *(const bf16x8*)(mr + ks * 32);
      #pragma unroll
      for (int j = 0; j < 8; ++j)
        xacc[ks][j] += bf2f((unsigned short)v[j]);
    }
  }

  bf16x8 xf[4], hf[4];
  #pragma unroll
  for (int ks = 0; ks < 4; ++ks) {
    bf16x8 v;
    #pragma unroll
    for (int j = 0; j < 8; ++j) v[j] = (short)f2bf(xacc[ks][j]);
    xf[ks] = v;
  }
  const unsigned short* hrow = lsb + (size_t)ec * DIM + quad * 8;
  #pragma unroll
  for (int ks = 0; ks < 4; ++ks) hf[ks] = *(const bf16x8*)(hrow + ks * 32);

  const bf16x8* Wzrf = (const bf16x8*)Wzrp;
  const bf16x8* Wkhf = (const bf16x8*)Wkhp;
  const bf16x8* Wrhf = (const bf16x8*)Wrhp;
  const float4* gbv  = (const float4*)gb;

  // per n-column: only 4 live accumulators -> low VGPR, high occupancy
  #pragma unroll 1
  for (int nf = 0; nf < 8; ++nf) {
    f32x4 az = (f32x4)(0.f), ar = (f32x4)(0.f);
    f32x4 axh = (f32x4)(0.f), ahh = (f32x4)(0.f);
    #pragma unroll
    for (int ks = 0; ks < 8; ++ks) {
      bf16x8 bb = (ks < 4) ? xf[ks] : hf[ks - 4];
      az = MFMA(Wzrf[(ks * 16 + nf) * 64 + lane], bb, az);
      ar = MFMA(Wzrf[(ks * 16 + nf + 8) * 64 + lane], bb, ar);
    }
    #pragma unroll
    for (int ks = 0; ks < 4; ++ks) {
      axh = MFMA(Wkhf[(ks * 8 + nf) * 64 + lane], xf[ks], axh);
      ahh = MFMA(Wrhf[(ks * 8 + nf) * 64 + lane], hf[ks], ahh);
    }

    if (e < NUM_E) {
      int n0 = nf * 16 + quad * 4;
      int q4 = nf * 4 + quad;
      float4 b0z = gbv[q4],       b0r = gbv[32 + q4],  b0h = gbv[64 + q4];
      float4 b1z = gbv[96 + q4],  b1r = gbv[128 + q4], b1h = gbv[160 + q4];
      // hold = carried bf16 h (row already hot in L1 from the hf reads)
      ushort4 hraw = *(const ushort4*)(lsb + (size_t)e * DIM + n0);
      float ho[4] = { bf2f(hraw.x), bf2f(hraw.y), bf2f(hraw.z), bf2f(hraw.w) };
      const float* pz  = (const float*)&az;
      const float* pr  = (const float*)&ar;
      const float* pxh = (const float*)&axh;
      const float* phh = (const float*)&ahh;
      const float* b0za = (const float*)&b0z; const float* b0ra = (const float*)&b0r;
      const float* b0ha = (const float*)&b0h; const float* b1za = (const float*)&b1z;
      const float* b1ra = (const float*)&b1r; const float* b1ha = (const float*)&b1h;
      ushort4 pk;
      {
        float z  = sigmoidf_(pz[0] + b0za[0] + b1za[0]);
        float r  = sigmoidf_(pr[0] + b0ra[0] + b1ra[0]);
        float hc = tanhf_(pxh[0] + b0ha[0] + r * (phh[0] + b1ha[0]));
        pk.x = f2bf(z * ho[0] + (1.f - z) * hc);
      }
      {
        float z  = sigmoidf_(pz[1] + b0za[1] + b1za[1]);
        float r  = sigmoidf_(pr[1] + b0ra[1] + b1ra[1]);
        float hc = tanhf_(pxh[1] + b0ha[1] + r * (phh[1] + b1ha[1]));
        pk.y = f2bf(z * ho[1] + (1.f - z) * hc);
      }
      {
        float z  = sigmoidf_(pz[2] + b0za[2] + b1za[2]);
        float r  = sigmoidf_(pr[2] + b0ra[2] + b1ra[2]);
        float hc = tanhf_(pxh[2] + b0ha[2] + r * (phh[2] + b1ha[2]));
        pk.z = f2bf(z * ho[2] + (1.f - z) * hc);
      }
      {
        float z  = sigmoidf_(pz[3] + b0za[3] + b1za[3]);
        float r  = sigmoidf_(pr[3] + b0ra[3] + b1ra[3]);
        float hc = tanhf_(pxh[3] + b0ha[3] + r * (phh[3] + b1ha[3]));
        pk.w = f2bf(z * ho[3] + (1.f - z) * hc);
      }
      *(ushort4*)(lsb + (size_t)e * DIM + n0) = pk;
    }
  }
}

// ---------------- graph segment-sum (sorted ids; reads bf16 h, fp32 accum) ----------------
__global__ __launch_bounds__(256) void graph_sum_kernel(
    const unsigned short* __restrict__ lsb, const int* __restrict__ gids,
    float* __restrict__ gs) {
  const int t = threadIdx.x;
  const int d = t & 127;
  const int half = t >> 7;
  const int e0 = blockIdx.x * GS_ER;
  const int e1 = min(e0 + GS_ER, NUM_E);
  float acc = 0.f;
  int cur = -1;
  for (int e = e0 + half; e < e1; e += 2) {
    int g = gids[e];
    if (g != cur) {
      if (cur >= 0) atomicAdd(&gs[cur * DIM + d], acc);
      acc = 0.f;
      cur = g;
    }
    acc += bf2f(lsb[(size_t)e * DIM + d]);
  }
  if (cur >= 0) atomicAdd(&gs[cur * DIM + d], acc);
}

// ---------------- fused readout: 3 layers in one kernel ----------------
__global__ __launch_bounds__(256) void readout_kernel(
    const float* __restrict__ gs,
    const float* __restrict__ rW1, const float* __restrict__ rb1,
    const float* __restrict__ rW2, const float* __restrict__ rb2,
    const float* __restrict__ rW3, const float* __restrict__ rb3,
    float* __restrict__ out) {
  __shared__ float shg[DIM];
  __shared__ float sh1[HID];
  __shared__ float red[HID];
  int g = blockIdx.x, c = threadIdx.x;
  if (c < DIM) shg[c] = gs[g * DIM + c];
  __syncthreads();
  float s = rb1[c];
  for (int k = 0; k < DIM; ++k) s += shg[k] * rW1[k * HID + c];
  sh1[c] = relu_(s);
  __syncthreads();
  s = rb2[c];
  for (int k = 0; k < HID; ++k) s += sh1[k] * rW2[k * HID + c];
  red[c] = relu_(s) * rW3[c];
  __syncthreads();
  for (int off = 128; off > 0; off >>= 1) {
    if (c < off) red[c] += red[c + off];
    __syncthreads();
  }
  if (c == 0) out[g] = red[0] + rb3[0];
}

extern "C" void kernel_launch(void* const* d_in, const int* in_sizes, int n_in,
                              void* d_out, int out_size, void* d_ws, size_t ws_size,
                              hipStream_t stream) {
  float* ls          = (float*)d_in[0];        // fp32 link_state (read-only here)
  const int* first   = (const int*)d_in[1];
  const int* second  = (const int*)d_in[2];
  const int* gids    = (const int*)d_in[3];
  const float* mW1   = (const float*)d_in[5];
  const float* mb1   = (const float*)d_in[6];
  const float* mW2   = (const float*)d_in[7];
  const float* mb2   = (const float*)d_in[8];
  const float* gk    = (const float*)d_in[9];
  const float* gr    = (const float*)d_in[10];
  const float* gb    = (const float*)d_in[11];
  const float* rW1   = (const float*)d_in[12];
  const float* rb1   = (const float*)d_in[13];
  const float* rW2   = (const float*)d_in[14];
  const float* rb2   = (const float*)d_in[15];
  const float* rW3   = (const float*)d_in[16];
  const float* rb3   = (const float*)d_in[17];
  float* out = (float*)d_out;

  // workspace layout
  char* w = (char*)d_ws;
  unsigned short* msgb = (unsigned short*)w;    w += (size_t)NUM_M * DIM * 2;   // 51.2 MB
  unsigned short* lsb  = (unsigned short*)w;    w += (size_t)NUM_E * DIM * 2;   // 25.6 MB
  float* gs    = (float*)w;                     w += NG * DIM * 4;
  int* counts  = (int*)w;                       w += NUM_E * 4;
  int* cursor  = (int*)w;                       w += NUM_E * 4;   // adjacent to counts
  int* rowptr  = (int*)w;                       w += (NUM_E + 4) * 4;
  int* order   = (int*)w;                       w += NUM_M * 4;
  int* partials= (int*)w;                       w += NB_SCAN * 4;
  int* basep   = (int*)w;                       w += NB_SCAN * 4;
  unsigned short* W1p  = (unsigned short*)w;    w += 256 * 256 * 2;
  unsigned short* W2p  = (unsigned short*)w;    w += 256 * 128 * 2;
  unsigned short* Wzrp = (unsigned short*)w;    w += 256 * 256 * 2;
  unsigned short* Wkhp = (unsigned short*)w;    w += 128 * 128 * 2;
  unsigned short* Wrhp = (unsigned short*)w;    w += 128 * 128 * 2;

  // prep: bf16 link_state + all weight packs, one launch
  const int n4 = NUM_E * DIM / 4;
  prep_kernel<<<(n4 + 255) / 256, 256, 0, stream>>>(
      (const float4*)ls, (ushort4*)lsb, n4, mW1, mW2, gk, gr,
      W1p, W2p, Wzrp, Wkhp, Wrhp);

  // CSR build (parallel 3-kernel scan)
  hipMemsetAsync(counts, 0, 2 * (size_t)NUM_E * 4, stream);   // counts + cursor
  hist_kernel<<<(NUM_M + 255) / 256, 256, 0, stream>>>(second, counts, (float4*)gs);
  scan1_kernel<<<NB_SCAN, 256, 0, stream>>>(counts, partials);
  scan2_kernel<<<1, 64, 0, stream>>>(partials, basep, rowptr);
  scan3_kernel<<<NB_SCAN, 256, 0, stream>>>(counts, basep, rowptr);
  scatter_kernel<<<(NUM_M + 255) / 256, 256, 0, stream>>>(second, rowptr, cursor, order);

  const int gruBlocks = (NUM_E + 63) / 64;
  for (int t = 0; t < TITER; ++t) {
    msg_kernel<<<512, 256, 0, stream>>>(lsb, first, second, order, W1p, mb1, W2p, mb2, msgb);
    gru_kernel<<<gruBlocks, 256, 0, stream>>>(msgb, rowptr, lsb, Wzrp, Wkhp, Wrhp, gb);
  }
  graph_sum_kernel<<<(NUM_E + GS_ER - 1) / GS_ER, 256, 0, stream>>>(lsb, gids, gs);
  readout_kernel<<<NG, HID, 0, stream>>>(gs, rW1, rb1, rW2, rb2, rW3, rb3, out);
}